// Round 4
// baseline (583.041 us; speedup 1.0000x reference)
//
#include <hip/hip_runtime.h>
#include <math.h>

#define B_     32
#define N_     20
#define D_     64
#define NODE_F 16
#define EDGE_F 8
#define E_PER  40
#define PROP   5
#define NC2    190
#define ITERS  20
#define INV_TEMP 10.0f
#define TN (2*B_*N_)
#define TE (2*B_*E_PER)
#define NG (2*B_)

struct PairTab { int s[NC2]; int d[NC2]; };
constexpr PairTab make_pairs() {
    PairTab t{};
    int idx = 0;
    for (int i = 0; i < N_; ++i)
        for (int j = i + 1; j < N_; ++j) { t.s[idx] = i; t.d[idx] = j; ++idx; }
    return t;
}
__device__ constexpr PairTab PAIRS = make_pairs();

__device__ __forceinline__ float rlane(float x, int k) {
    return __int_as_float(__builtin_amdgcn_readlane(__float_as_int(x), k));
}
template<int CTRL>
__device__ __forceinline__ float dppmov(float x) {
    return __int_as_float(__builtin_amdgcn_update_dpp(
        0, __float_as_int(x), CTRL, 0xf, 0xf, false));
}
__device__ __forceinline__ float rowsum16(float x) {
    x += dppmov<0x121>(x); x += dppmov<0x122>(x);
    x += dppmov<0x124>(x); x += dppmov<0x128>(x);
    return x;
}
__device__ __forceinline__ float rowmax16(float x) {
    x = fmaxf(x, dppmov<0x121>(x)); x = fmaxf(x, dppmov<0x122>(x));
    x = fmaxf(x, dppmov<0x124>(x)); x = fmaxf(x, dppmov<0x128>(x));
    return x;
}
__device__ __forceinline__ float nrcp(float x) {
    float r = __builtin_amdgcn_rcpf(x);
    r = r * fmaf(-x, r, 2.0f);
    return r;
}

// ================= fused per-batch pipeline: encode + 5xprop + sim + edge + sink190
__global__ __launch_bounds__(1024) void k_mega(
    const float* __restrict__ nf, const float* __restrict__ ef,
    const float* __restrict__ qadj, const float* __restrict__ cadj,
    const int* __restrict__ fidx, const int* __restrict__ tidx,
    const float* __restrict__ Wn, const float* __restrict__ bn,
    const float* __restrict__ We, const float* __restrict__ be,
    const float* __restrict__ Wm1, const float* __restrict__ bm1,
    const float* __restrict__ Wm2, const float* __restrict__ bm2,
    const float* __restrict__ Wu1, const float* __restrict__ bu1,
    const float* __restrict__ Wu2, const float* __restrict__ bu2,
    const float* __restrict__ Ws1, const float* __restrict__ bs1,
    const float* __restrict__ Ws2, const float* __restrict__ bs2,
    const float* __restrict__ Wl1, const float* __restrict__ bl1,
    const float* __restrict__ Wl2, const float* __restrict__ bl2,
    float* __restrict__ emb, float* __restrict__ eplan, float* __restrict__ dout)
{
    __shared__ float sh_h[40][64];      // 10240 B, node states (2 graphs)
    __shared__ short sFr[80], sTo[80];  // 320 B
    __shared__ short sQs[192], sQd[192];// 768 B
    __shared__ float sP[N_][N_];        // 1600 B
    __shared__ float sVbuf[192];        // 768 B
    __shared__ float region[12416];     // 49664 B (union: prop / sim / colbuf)
    float* eemb = region;               // [80][64]
    float* agg  = region + 80 * 64;     // [40][64]
    float* sT   = region;               // [2][20][20] (sim phase)
    float* sLa  = region + 800;         // [20][20]
    float* colbuf = region;             // [64][194]

    int b = blockIdx.x, t = threadIdx.x, w = t >> 6, l = t & 63;

    // ---------------- encode ----------------
    if (t < 80) {
        sFr[t] = (short)(fidx[b * 80 + t] - b * 40);
        sTo[t] = (short)(tidx[b * 80 + t] - b * 40);
    }
    if (t < 192) {
        int tt = t < NC2 ? t : NC2 - 1;
        sQs[t] = (short)PAIRS.s[tt]; sQd[t] = (short)PAIRS.d[tt];
    }
    if (t == 0) dout[b] = 0.f;
#pragma unroll
    for (int s = 0; s < 3; ++s) {
        int r = w + 16 * s;
        if (r < 40) {
            float acc = bn[l];
#pragma unroll
            for (int k = 0; k < NODE_F; ++k) acc += nf[(b * 40 + r) * NODE_F + k] * Wn[k * 64 + l];
            sh_h[r][l] = acc;
        }
    }
#pragma unroll
    for (int s = 0; s < 5; ++s) {
        int e = w * 5 + s;
        float acc = be[l];
#pragma unroll
        for (int k = 0; k < EDGE_F; ++k) acc += ef[(b * 80 + e) * EDGE_F + k] * We[k * 64 + l];
        eemb[e * 64 + l] = acc;
    }
    for (int idx = t; idx < 2560; idx += 1024) agg[idx] = 0.f;
    __syncthreads();

    // ---------------- 5x propagation ----------------
    for (int step = 0; step < PROP; ++step) {
        // message MLP: 5 edges per wave
        int eb = w * 5;
        float xf[5], xt[5], xe[5]; int dst[5];
#pragma unroll
        for (int s = 0; s < 5; ++s) {
            int fr = sFr[eb + s]; dst[s] = sTo[eb + s];
            xf[s] = sh_h[fr][l];
            xt[s] = sh_h[dst[s]][l];
            xe[s] = eemb[(eb + s) * 64 + l];
        }
        float b1 = bm1[l];
        float acc[5];
#pragma unroll
        for (int s = 0; s < 5; ++s) acc[s] = b1;
#pragma unroll 4
        for (int k = 0; k < 64; ++k) {
            float w0 = Wm1[k * 64 + l];
            float w1 = Wm1[(64 + k) * 64 + l];
            float w2 = Wm1[(128 + k) * 64 + l];
#pragma unroll
            for (int s = 0; s < 5; ++s)
                acc[s] += rlane(xf[s], k) * w0 + rlane(xt[s], k) * w1 + rlane(xe[s], k) * w2;
        }
        float b2 = bm2[l];
        float out[5];
#pragma unroll
        for (int s = 0; s < 5; ++s) { acc[s] = fmaxf(acc[s], 0.f); out[s] = b2; }
#pragma unroll 4
        for (int k = 0; k < 64; ++k) {
            float ww = Wm2[k * 64 + l];
#pragma unroll
            for (int s = 0; s < 5; ++s) out[s] += rlane(acc[s], k) * ww;
        }
#pragma unroll
        for (int s = 0; s < 5; ++s) atomicAdd(&agg[dst[s] * 64 + l], out[s]);
        __syncthreads();

        // node update: nodes w, w+16, w+32(w<8)
        float xh[3], xa[3];
        bool nv[3] = {true, true, (w < 8)};
#pragma unroll
        for (int s = 0; s < 3; ++s) {
            int r = w + 16 * s;
            if (nv[s]) { xh[s] = sh_h[r][l]; xa[s] = agg[r * 64 + l]; }
            else { xh[s] = 0.f; xa[s] = 0.f; }
        }
        float c1 = bu1[l];
        float a2[3];
#pragma unroll
        for (int s = 0; s < 3; ++s) a2[s] = c1;
#pragma unroll 4
        for (int k = 0; k < 64; ++k) {
            float wa = Wu1[k * 64 + l];
            float wb = Wu1[(64 + k) * 64 + l];
#pragma unroll
            for (int s = 0; s < 3; ++s)
                a2[s] += rlane(xh[s], k) * wa + rlane(xa[s], k) * wb;
        }
        float c2 = bu2[l];
        float o2[3];
#pragma unroll
        for (int s = 0; s < 3; ++s) { a2[s] = fmaxf(a2[s], 0.f); o2[s] = c2; }
#pragma unroll 4
        for (int k = 0; k < 64; ++k) {
            float ww = Wu2[k * 64 + l];
#pragma unroll
            for (int s = 0; s < 3; ++s) o2[s] += rlane(a2[s], k) * ww;
        }
#pragma unroll
        for (int s = 0; s < 3; ++s) {
            int r = w + 16 * s;
            if (nv[s]) { sh_h[r][l] = o2[s]; agg[r * 64 + l] = 0.f; }
        }
        __syncthreads();
    }

    // ---------------- sim: T MLPs ----------------
    {
        int lk = (l < 20) ? l : 0;
#pragma unroll
        for (int s = 0; s < 3; ++s) {
            int r = w + 16 * s;
            if (r < 40) {
                float hv = sh_h[r][l];
                float a = bs1[lk];
#pragma unroll 4
                for (int ff = 0; ff < 64; ++ff) a += rlane(hv, ff) * Ws1[ff * 20 + lk];
                a = fmaxf(a, 0.f);
                float t2 = bs2[lk];
#pragma unroll
                for (int j = 0; j < 20; ++j) t2 += rlane(a, j) * Ws2[j * 20 + lk];
                if (l < 20) sT[(r >= 20) * 400 + (r % 20) * 20 + l] = t2;
            }
        }
    }
    __syncthreads();
    if (t < 400) {
        int i = t / 20, j = t % 20;
        float c = 0.f;
#pragma unroll
        for (int k = 0; k < 20; ++k) c += fabsf(sT[i * 20 + k] - sT[400 + j * 20 + k]);
        sLa[i * 20 + j] = -c * INV_TEMP;
    }
    __syncthreads();

    // ---------------- single-wave register 20x20 log sinkhorn ----------------
    if (w == 0) {
        int q = l & 31, r2 = l >> 5;
        bool qok = (q < 20);
        float A20[10], u10[10];
#pragma unroll
        for (int i = 0; i < 10; ++i) {
            int r = 2 * i + r2;
            A20[i] = qok ? sLa[r * 20 + q] : -1e30f;
        }
        float vq = 0.f;
        for (int it = 0; it < ITERS; ++it) {
            // row LSE within each 32-lane half
#pragma unroll
            for (int i = 0; i < 10; ++i) {
                float x = A20[i] - vq;
                float m = x;
#pragma unroll
                for (int off = 16; off; off >>= 1) m = fmaxf(m, __shfl_xor(m, off));
                float s = __expf(x - m);
#pragma unroll
                for (int off = 16; off; off >>= 1) s += __shfl_xor(s, off);
                u10[i] = m + __logf(s);
            }
            // col LSE: per-lane over 10 rows, merge halves via xor(32)
            float pm = -1e30f;
#pragma unroll
            for (int i = 0; i < 10; ++i) pm = fmaxf(pm, A20[i] - u10[i]);
            float ps = 0.f;
#pragma unroll
            for (int i = 0; i < 10; ++i) ps += __expf(A20[i] - u10[i] - pm);
            float om = __shfl_xor(pm, 32), os = __shfl_xor(ps, 32);
            float M = fmaxf(pm, om);
            float S = ps * __expf(pm - M) + os * __expf(om - M);
            vq = M + __logf(S);
            if (!qok) vq = 0.f;   // keep invalid lanes inert
        }
#pragma unroll
        for (int i = 0; i < 10; ++i) {
            int r = 2 * i + r2;
            if (qok) sP[r][q] = __expf(A20[i] - u10[i] - vq);
        }
    }
    __syncthreads();

    // ---------------- edge MLPs (fwd+bwd fused), streamed to global ----------------
    {
        float b1 = bl1[l];
        float w128 = Wl1[128 * 64 + l];
        float b2 = 2.f * bl2[l];
        for (int bs = 0; bs < 6; ++bs) {
            int base = w * 24 + bs * 4;
            float sv[4], dv[4], av[4]; bool val[4]; int gg[4], pp[4];
#pragma unroll
            for (int s = 0; s < 4; ++s) {
                int pl = base + s;
                val[s] = (pl < 380);
                int plc = val[s] ? pl : 0;
                gg[s] = (plc >= 190) ? 1 : 0;
                pp[s] = plc - gg[s] * 190;
                int sp = sQs[pp[s]], dp = sQd[pp[s]];
                sv[s] = sh_h[gg[s] * 20 + sp][l];
                dv[s] = sh_h[gg[s] * 20 + dp][l];
                const float* adj = gg[s] ? cadj : qadj;
                av[s] = adj[b * 400 + sp * 20 + dp];
            }
            float aF[4], aB[4];
#pragma unroll
            for (int s = 0; s < 4; ++s) { float t0 = b1 + av[s] * w128; aF[s] = t0; aB[s] = t0; }
#pragma unroll 2
            for (int k = 0; k < 64; ++k) {
                float w0 = Wl1[k * 64 + l];
                float w1 = Wl1[(64 + k) * 64 + l];
#pragma unroll
                for (int s = 0; s < 4; ++s) {
                    float a = rlane(sv[s], k), c = rlane(dv[s], k);
                    aF[s] += a * w0 + c * w1;
                    aB[s] += c * w0 + a * w1;
                }
            }
            float hs[4], out[4];
#pragma unroll
            for (int s = 0; s < 4; ++s) { hs[s] = fmaxf(aF[s], 0.f) + fmaxf(aB[s], 0.f); out[s] = b2; }
#pragma unroll 4
            for (int k = 0; k < 64; ++k) {
                float ww = Wl2[k * 64 + l];
#pragma unroll
                for (int s = 0; s < 4; ++s) out[s] += rlane(hs[s], k) * ww;
            }
#pragma unroll
            for (int s = 0; s < 4; ++s)
                if (val[s]) emb[((size_t)(2 * b + gg[s]) * NC2 + pp[s]) * 64 + l] = out[s];
        }
    }
    __syncthreads();   // region reuse: colbuf overwrites sim scratch

    // ---------------- sink190: log-domain iter 1, multiplicative iters 2..20 ----------------
    {
        int g4 = l >> 4, l16 = l & 15;
        int rslot = w * 4 + g4;

        int sp[3], dp[3]; bool pv[3];
#pragma unroll
        for (int i = 0; i < 3; ++i) {
            int p = rslot + 64 * i;
            pv[i] = (p < NC2);
            int pc = pv[i] ? p : 0;
            sp[i] = sQs[pc]; dp[i] = sQd[pc];
        }
        int sq[12], dq[12]; bool qv[12];
#pragma unroll
        for (int j = 0; j < 12; ++j) {
            int q = l16 + 16 * j;
            qv[j] = (q < NC2);
            int qc = qv[j] ? q : 0;
            sq[j] = sQs[qc]; dq[j] = sQd[qc];
        }

        // A = log-domain scores (invalid -> -1e30)
        float A[3][12];
#pragma unroll
        for (int i = 0; i < 3; ++i)
#pragma unroll
            for (int j = 0; j < 12; ++j) {
                if (pv[i] && qv[j]) {
                    float st = sP[sp[i]][sq[j]] * sP[dp[i]][dq[j]];
                    float cr = sP[sp[i]][dq[j]] * sP[dp[i]][sq[j]];
                    A[i][j] = __logf(fmaxf(st, cr) + 1e-6f) * INV_TEMP;
                } else A[i][j] = -1e30f;
            }

        // iter 1 row LSE (DPP across 16 lanes)
        float u[3];
#pragma unroll
        for (int i = 0; i < 3; ++i) {
            float m = -1e30f;
#pragma unroll
            for (int j = 0; j < 12; ++j) m = fmaxf(m, A[i][j]);
            m = rowmax16(m);
            float s = 0.f;
#pragma unroll
            for (int j = 0; j < 12; ++j) s += __expf(A[i][j] - m);
            s = rowsum16(s);
            u[i] = m + __logf(s);
            if (!pv[i]) u[i] = 0.f;
        }
        // iter 1 col LSE: pass A (max), pass B (sum)
#pragma unroll
        for (int j = 0; j < 12; ++j) {
            float pm = -1e30f;
#pragma unroll
            for (int i = 0; i < 3; ++i) if (pv[i]) pm = fmaxf(pm, A[i][j] - u[i]);
            colbuf[rslot * 194 + l16 + 16 * j] = pm;
        }
        __syncthreads();
        if (t < 192) {
            float M = -1e30f;
#pragma unroll
            for (int s = 0; s < 64; ++s) M = fmaxf(M, colbuf[s * 194 + t]);
            sVbuf[t] = M;
        }
        __syncthreads();
        float Mj[12];
#pragma unroll
        for (int j = 0; j < 12; ++j) Mj[j] = sVbuf[l16 + 16 * j];
#pragma unroll
        for (int j = 0; j < 12; ++j) {
            float ps = 0.f;
#pragma unroll
            for (int i = 0; i < 3; ++i) if (pv[i]) ps += __expf(A[i][j] - u[i] - Mj[j]);
            colbuf[rslot * 194 + l16 + 16 * j] = ps;
        }
        __syncthreads();
        if (t < 192) {
            float S = 0.f;
#pragma unroll
            for (int s = 0; s < 64; ++s) S += colbuf[s * 194 + t];
            sVbuf[t] = sVbuf[t] + __logf(fmaxf(S, 1e-37f));
        }
        __syncthreads();
        // E = exp(A - u - v) (state after full iteration 1)
        float E[3][12];
#pragma unroll
        for (int j = 0; j < 12; ++j) Mj[j] = sVbuf[l16 + 16 * j];
#pragma unroll
        for (int i = 0; i < 3; ++i)
#pragma unroll
            for (int j = 0; j < 12; ++j) {
                float e = __expf(A[i][j] - u[i] - Mj[j]);
                E[i][j] = (pv[i] && qv[j]) ? e : 0.f;
            }
        __syncthreads();

        // iters 2..20 multiplicative
        float invS[3];
        for (int it = 0; it < ITERS - 1; ++it) {
#pragma unroll
            for (int i = 0; i < 3; ++i) {
                float s01 = E[i][0] + E[i][1], s23 = E[i][2] + E[i][3];
                float s45 = E[i][4] + E[i][5], s67 = E[i][6] + E[i][7];
                float s89 = E[i][8] + E[i][9], sab = E[i][10] + E[i][11];
                float S = ((s01 + s23) + (s45 + s67)) + (s89 + sab);
                S = rowsum16(S);
                invS[i] = nrcp(fmaxf(S, 1e-30f));
            }
#pragma unroll
            for (int j = 0; j < 12; ++j) {
                float pc = E[0][j] * invS[0];
                pc = fmaf(E[1][j], invS[1], pc);
                pc = fmaf(E[2][j], invS[2], pc);
                colbuf[rslot * 194 + l16 + 16 * j] = pc;
            }
            __syncthreads();
            if (t < 192) {
                float a0 = 0.f, a1 = 0.f, a2 = 0.f, a3 = 0.f;
#pragma unroll
                for (int s = 0; s < 16; ++s) {
                    a0 += colbuf[(4 * s + 0) * 194 + t];
                    a1 += colbuf[(4 * s + 1) * 194 + t];
                    a2 += colbuf[(4 * s + 2) * 194 + t];
                    a3 += colbuf[(4 * s + 3) * 194 + t];
                }
                float c = (a0 + a1) + (a2 + a3);
                sVbuf[t] = nrcp(fmaxf(c, 1e-30f));
            }
            __syncthreads();
            float ic[12];
#pragma unroll
            for (int j = 0; j < 12; ++j) ic[j] = sVbuf[l16 + 16 * j];
#pragma unroll
            for (int i = 0; i < 3; ++i)
#pragma unroll
                for (int j = 0; j < 12; ++j) {
                    float tmp = E[i][j] * invS[i];
                    E[i][j] = tmp * ic[j];
                }
        }

        // write eplan
        float* ep = eplan + (size_t)b * NC2 * NC2;
#pragma unroll
        for (int i = 0; i < 3; ++i) {
            if (pv[i]) {
                int p = rslot + 64 * i;
                float* row = ep + (size_t)p * NC2;
#pragma unroll
                for (int j = 0; j < 12; ++j)
                    if (qv[j]) row[l16 + 16 * j] = E[i][j];
            }
        }
    }
}

// ================= final weighted L1 contraction =================
__global__ __launch_bounds__(256) void k_dist(
    const float* __restrict__ emb, const float* __restrict__ eplan, float* __restrict__ dout)
{
    int b = blockIdx.x, c = blockIdx.y;
    int w = threadIdx.x >> 6, l = threadIdx.x & 63;
    const float* qe = emb + (size_t)(2 * b) * NC2 * D_;
    const float* ce = emb + (size_t)(2 * b + 1) * NC2 * D_;
    const float* W = eplan + (size_t)b * NC2 * NC2;
    float acc = 0.f;
    int pbase = c * 16 + w * 4;
    for (int i = 0; i < 4; ++i) {
        int p = pbase + i;
        if (p >= NC2) break;
        float qv = qe[(size_t)p * D_ + l];
        const float* wrow = W + (size_t)p * NC2;
        for (int q = 0; q < NC2; ++q)
            acc += wrow[q] * fabsf(qv - ce[(size_t)q * D_ + l]);
    }
#pragma unroll
    for (int off = 32; off; off >>= 1) acc += __shfl_xor(acc, off);
    if (l == 0) atomicAdd(&dout[b], acc);
}

// ================= launch =================
extern "C" void kernel_launch(void* const* d_in, const int* in_sizes, int n_in,
                              void* d_out, int out_size, void* d_ws, size_t ws_size,
                              hipStream_t stream)
{
    const float* nf   = (const float*)d_in[0];
    const float* ef   = (const float*)d_in[1];
    const float* qadj = (const float*)d_in[2];
    const float* cadj = (const float*)d_in[3];
    const int*   fidx = (const int*)d_in[4];
    const int*   tidx = (const int*)d_in[5];
    const float* Wn  = (const float*)d_in[6];  const float* bn  = (const float*)d_in[7];
    const float* We  = (const float*)d_in[8];  const float* be  = (const float*)d_in[9];
    const float* Wm1 = (const float*)d_in[10]; const float* bm1 = (const float*)d_in[11];
    const float* Wm2 = (const float*)d_in[12]; const float* bm2 = (const float*)d_in[13];
    const float* Wu1 = (const float*)d_in[14]; const float* bu1 = (const float*)d_in[15];
    const float* Wu2 = (const float*)d_in[16]; const float* bu2 = (const float*)d_in[17];
    const float* Ws1 = (const float*)d_in[18]; const float* bs1 = (const float*)d_in[19];
    const float* Ws2 = (const float*)d_in[20]; const float* bs2 = (const float*)d_in[21];
    const float* Wl1 = (const float*)d_in[22]; const float* bl1 = (const float*)d_in[23];
    const float* Wl2 = (const float*)d_in[24]; const float* bl2 = (const float*)d_in[25];

    float* ws    = (float*)d_ws;
    float* emb   = ws;                              // NG*NC2*D
    float* eplan = emb + (size_t)NG * NC2 * D_;     // B*NC2*NC2
    float* dout  = (float*)d_out;

    k_mega<<<B_, 1024, 0, stream>>>(nf, ef, qadj, cadj, fidx, tidx,
                                    Wn, bn, We, be, Wm1, bm1, Wm2, bm2,
                                    Wu1, bu1, Wu2, bu2, Ws1, bs1, Ws2, bs2,
                                    Wl1, bl1, Wl2, bl2, emb, eplan, dout);
    k_dist<<<dim3(B_, 12), 256, 0, stream>>>(emb, eplan, dout);
}

// Round 7
// 375.563 us; speedup vs baseline: 1.5524x; 1.5524x over previous
//
#include <hip/hip_runtime.h>
#include <math.h>

#define B_     32
#define N_     20
#define D_     64
#define NODE_F 16
#define EDGE_F 8
#define E_PER  40
#define PROP   5
#define NC2    190
#define ITERS  20
#define INV_TEMP 10.0f
#define TN (2*B_*N_)
#define NG (2*B_)

struct PairTab { int s[NC2]; int d[NC2]; };
constexpr PairTab make_pairs() {
    PairTab t{};
    int idx = 0;
    for (int i = 0; i < N_; ++i)
        for (int j = i + 1; j < N_; ++j) { t.s[idx] = i; t.d[idx] = j; ++idx; }
    return t;
}
__device__ constexpr PairTab PAIRS = make_pairs();

__device__ __forceinline__ float rlane(float x, int k) {
    return __int_as_float(__builtin_amdgcn_readlane(__float_as_int(x), k));
}
template<int CTRL>
__device__ __forceinline__ float dppmov(float x) {
    return __int_as_float(__builtin_amdgcn_update_dpp(
        0, __float_as_int(x), CTRL, 0xf, 0xf, false));
}
__device__ __forceinline__ float rowsum16(float x) {
    x += dppmov<0x121>(x); x += dppmov<0x122>(x);
    x += dppmov<0x124>(x); x += dppmov<0x128>(x);
    return x;
}
__device__ __forceinline__ float rowmax16(float x) {
    x = fmaxf(x, dppmov<0x121>(x)); x = fmaxf(x, dppmov<0x122>(x));
    x = fmaxf(x, dppmov<0x124>(x)); x = fmaxf(x, dppmov<0x128>(x));
    return x;
}
__device__ __forceinline__ float nrcp(float x) {
    float r = __builtin_amdgcn_rcpf(x);
    r = r * fmaf(-x, r, 2.0f);
    return r;
}

// ================= per-graph: encode + 5x(msg,update), all state in LDS =================
__global__ __launch_bounds__(640) void k_prop(
    const float* __restrict__ nf, const float* __restrict__ ef,
    const int* __restrict__ fidx, const int* __restrict__ tidx,
    const float* __restrict__ Wn, const float* __restrict__ bn,
    const float* __restrict__ We, const float* __restrict__ be,
    const float* __restrict__ Wm1, const float* __restrict__ bm1,
    const float* __restrict__ Wm2, const float* __restrict__ bm2,
    const float* __restrict__ Wu1, const float* __restrict__ bu1,
    const float* __restrict__ Wu2, const float* __restrict__ bu2,
    float* __restrict__ hout)
{
    __shared__ float sh[20][64];   // node states
    __shared__ float se[40][64];   // edge embeddings
    __shared__ float sa[20][64];   // aggregation
    __shared__ short sF[40], sD[40];
    int g = blockIdx.x, t = threadIdx.x, w = t >> 6, l = t & 63;

    if (t < 40) {
        sF[t] = (short)(fidx[g * 40 + t] - g * 20);
        sD[t] = (short)(tidx[g * 40 + t] - g * 20);
    }
    // encode nodes: 2 per wave
#pragma unroll
    for (int s = 0; s < 2; ++s) {
        int n = 2 * w + s;
        float a = bn[l];
#pragma unroll
        for (int k = 0; k < NODE_F; ++k) a += nf[(g * 20 + n) * NODE_F + k] * Wn[k * 64 + l];
        sh[n][l] = a; sa[n][l] = 0.f;
    }
    // encode edges: 4 per wave
#pragma unroll
    for (int s = 0; s < 4; ++s) {
        int e = 4 * w + s;
        float a = be[l];
#pragma unroll
        for (int k = 0; k < EDGE_F; ++k) a += ef[(g * 40 + e) * EDGE_F + k] * We[k * 64 + l];
        se[e][l] = a;
    }
    __syncthreads();

    for (int step = 0; step < PROP; ++step) {
        // ---- message MLP: 4 edges per wave
        float xf[4], xt[4], xe[4]; int dst[4];
#pragma unroll
        for (int s = 0; s < 4; ++s) {
            int e = 4 * w + s;
            int fr = sF[e]; dst[s] = sD[e];
            xf[s] = sh[fr][l]; xt[s] = sh[dst[s]][l]; xe[s] = se[e][l];
        }
        float b1 = bm1[l];
        float acc[4];
#pragma unroll
        for (int s = 0; s < 4; ++s) acc[s] = b1;
#pragma unroll 4
        for (int k = 0; k < 64; ++k) {
            float w0 = Wm1[k * 64 + l];
            float w1 = Wm1[(64 + k) * 64 + l];
            float w2 = Wm1[(128 + k) * 64 + l];
#pragma unroll
            for (int s = 0; s < 4; ++s)
                acc[s] += rlane(xf[s], k) * w0 + rlane(xt[s], k) * w1 + rlane(xe[s], k) * w2;
        }
        float b2 = bm2[l];
        float out[4];
#pragma unroll
        for (int s = 0; s < 4; ++s) { acc[s] = fmaxf(acc[s], 0.f); out[s] = b2; }
#pragma unroll 4
        for (int k = 0; k < 64; ++k) {
            float ww = Wm2[k * 64 + l];
#pragma unroll
            for (int s = 0; s < 4; ++s) out[s] += rlane(acc[s], k) * ww;
        }
#pragma unroll
        for (int s = 0; s < 4; ++s) atomicAdd(&sa[dst[s]][l], out[s]);
        __syncthreads();

        // ---- node update: 2 nodes per wave
        float xh[2], xa[2];
#pragma unroll
        for (int s = 0; s < 2; ++s) {
            int n = 2 * w + s;
            xh[s] = sh[n][l]; xa[s] = sa[n][l];
        }
        float c1 = bu1[l];
        float a2[2];
#pragma unroll
        for (int s = 0; s < 2; ++s) a2[s] = c1;
#pragma unroll 4
        for (int k = 0; k < 64; ++k) {
            float wa = Wu1[k * 64 + l];
            float wb = Wu1[(64 + k) * 64 + l];
#pragma unroll
            for (int s = 0; s < 2; ++s)
                a2[s] += rlane(xh[s], k) * wa + rlane(xa[s], k) * wb;
        }
        float c2 = bu2[l];
        float o2[2];
#pragma unroll
        for (int s = 0; s < 2; ++s) { a2[s] = fmaxf(a2[s], 0.f); o2[s] = c2; }
#pragma unroll 4
        for (int k = 0; k < 64; ++k) {
            float ww = Wu2[k * 64 + l];
#pragma unroll
            for (int s = 0; s < 2; ++s) o2[s] += rlane(a2[s], k) * ww;
        }
#pragma unroll
        for (int s = 0; s < 2; ++s) {
            int n = 2 * w + s;
            sh[n][l] = o2[s]; sa[n][l] = 0.f;
        }
        __syncthreads();
    }
#pragma unroll
    for (int s = 0; s < 2; ++s) {
        int n = 2 * w + s;
        hout[(g * 20 + n) * 64 + l] = sh[n][l];
    }
}

// ================= heterogeneous: blocks 0..31 sim+sink190, blocks 32..159 edge MLP =================
__global__ __launch_bounds__(1024, 4) void k_fuse(
    const float* __restrict__ h,
    const float* __restrict__ qadj, const float* __restrict__ cadj,
    const float* __restrict__ Ws1, const float* __restrict__ bs1,
    const float* __restrict__ Ws2, const float* __restrict__ bs2,
    const float* __restrict__ Wl1, const float* __restrict__ bl1,
    const float* __restrict__ Wl2, const float* __restrict__ bl2,
    float* __restrict__ emb, float* __restrict__ eplan, float* __restrict__ dout)
{
    __shared__ short sQs[192], sQd[192];
    __shared__ float sP[N_][N_];
    __shared__ float sVbuf[192];
    __shared__ float region[12800];   // colbuf [64][200]; sim phase: sT(800)+sLa(400)
    int t = threadIdx.x, w = t >> 6, l = t & 63;

    if (t < 192) {
        int tt = t < NC2 ? t : NC2 - 1;
        sQs[t] = (short)PAIRS.s[tt]; sQd[t] = (short)PAIRS.d[tt];
    }
    __syncthreads();

    if (blockIdx.x < 32) {
        // ======================= sim + sink190 role =======================
        int b = blockIdx.x;
        if (t == 0) dout[b] = 0.f;
        float* sT = region;
        float* sLa = region + 800;

        // T MLPs (h read from global, L1-hot)
        {
            int lk = (l < 20) ? l : 0;
#pragma unroll
            for (int s = 0; s < 3; ++s) {
                int r = w + 16 * s;
                if (r < 40) {
                    float hv = h[(b * 40 + r) * 64 + l];
                    float a = bs1[lk];
#pragma unroll 4
                    for (int ff = 0; ff < 64; ++ff) a += rlane(hv, ff) * Ws1[ff * 20 + lk];
                    a = fmaxf(a, 0.f);
                    float t2 = bs2[lk];
#pragma unroll
                    for (int j = 0; j < 20; ++j) t2 += rlane(a, j) * Ws2[j * 20 + lk];
                    if (l < 20) sT[(r >= 20) * 400 + (r % 20) * 20 + l] = t2;
                }
            }
        }
        __syncthreads();
        if (t < 400) {
            int i = t / 20, j = t % 20;
            float c = 0.f;
#pragma unroll
            for (int k = 0; k < 20; ++k) c += fabsf(sT[i * 20 + k] - sT[400 + j * 20 + k]);
            sLa[i * 20 + j] = -c * INV_TEMP;
        }
        __syncthreads();

        // single-wave register 20x20 log sinkhorn
        if (w == 0) {
            int q = l & 31, r2 = l >> 5;
            bool qok = (q < 20);
            float A20[10], u10[10];
#pragma unroll
            for (int i = 0; i < 10; ++i) {
                int r = 2 * i + r2;
                A20[i] = qok ? sLa[r * 20 + q] : -1e30f;
            }
            float vq = 0.f;
            for (int it = 0; it < ITERS; ++it) {
#pragma unroll
                for (int i = 0; i < 10; ++i) {
                    float x = A20[i] - vq;
                    float m = x;
#pragma unroll
                    for (int off = 16; off; off >>= 1) m = fmaxf(m, __shfl_xor(m, off));
                    float s = __expf(x - m);
#pragma unroll
                    for (int off = 16; off; off >>= 1) s += __shfl_xor(s, off);
                    u10[i] = m + __logf(s);
                }
                float pm = -1e30f;
#pragma unroll
                for (int i = 0; i < 10; ++i) pm = fmaxf(pm, A20[i] - u10[i]);
                float ps = 0.f;
#pragma unroll
                for (int i = 0; i < 10; ++i) ps += __expf(A20[i] - u10[i] - pm);
                float om = __shfl_xor(pm, 32), os = __shfl_xor(ps, 32);
                float M = fmaxf(pm, om);
                float S = ps * __expf(pm - M) + os * __expf(om - M);
                vq = M + __logf(S);
                if (!qok) vq = 0.f;
            }
#pragma unroll
            for (int i = 0; i < 10; ++i) {
                int r = 2 * i + r2;
                if (qok) sP[r][q] = __expf(A20[i] - u10[i] - vq);
            }
        }
        __syncthreads();

        // ---- sink190 ----
        int g4 = l >> 4, l16 = l & 15, rslot = w * 4 + g4;
        int sp[3], dp[3]; bool pv[3];
#pragma unroll
        for (int i = 0; i < 3; ++i) {
            int p = rslot + 64 * i;
            pv[i] = (p < NC2);
            int pc = pv[i] ? p : 0;
            sp[i] = sQs[pc]; dp[i] = sQd[pc];
        }
        int sq[12], dq[12]; bool qv[12];
#pragma unroll
        for (int j = 0; j < 12; ++j) {
            int q = l16 + 16 * j;
            qv[j] = (q < NC2);
            int qc = qv[j] ? q : 0;
            sq[j] = sQs[qc]; dq[j] = sQd[qc];
        }

        float AE[3][12];   // log scores, then in-place exp state
#pragma unroll
        for (int i = 0; i < 3; ++i)
#pragma unroll
            for (int j = 0; j < 12; ++j) {
                if (pv[i] && qv[j]) {
                    float st = sP[sp[i]][sq[j]] * sP[dp[i]][dq[j]];
                    float cr = sP[sp[i]][dq[j]] * sP[dp[i]][sq[j]];
                    AE[i][j] = __logf(fmaxf(st, cr) + 1e-6f) * INV_TEMP;
                } else AE[i][j] = -1e30f;
            }

        // iter 1: log-domain (prevents multiplicative underflow for all later iters)
        float u[3];
#pragma unroll
        for (int i = 0; i < 3; ++i) {
            float m = -1e30f;
#pragma unroll
            for (int j = 0; j < 12; ++j) m = fmaxf(m, AE[i][j]);
            m = rowmax16(m);
            float s = 0.f;
#pragma unroll
            for (int j = 0; j < 12; ++j) s += __expf(AE[i][j] - m);
            s = rowsum16(s);
            u[i] = m + __logf(s);
            if (!pv[i]) u[i] = 0.f;
        }
#pragma unroll
        for (int j = 0; j < 12; ++j) {
            float pm = -1e30f;
#pragma unroll
            for (int i = 0; i < 3; ++i) if (pv[i]) pm = fmaxf(pm, AE[i][j] - u[i]);
            region[rslot * 200 + l16 + 16 * j] = pm;
        }
        __syncthreads();
        if (t < 192) {
            float M = -1e30f;
#pragma unroll
            for (int s = 0; s < 64; ++s) M = fmaxf(M, region[s * 200 + t]);
            sVbuf[t] = M;
        }
        __syncthreads();
        float Mj[12];
#pragma unroll
        for (int j = 0; j < 12; ++j) Mj[j] = sVbuf[l16 + 16 * j];
#pragma unroll
        for (int j = 0; j < 12; ++j) {
            float ps = 0.f;
#pragma unroll
            for (int i = 0; i < 3; ++i) if (pv[i]) ps += __expf(AE[i][j] - u[i] - Mj[j]);
            region[rslot * 200 + l16 + 16 * j] = ps;
        }
        __syncthreads();
        if (t < 192) {
            float S = 0.f;
#pragma unroll
            for (int s = 0; s < 64; ++s) S += region[s * 200 + t];
            sVbuf[t] = sVbuf[t] + __logf(fmaxf(S, 1e-37f));
        }
        __syncthreads();
#pragma unroll
        for (int j = 0; j < 12; ++j) Mj[j] = sVbuf[l16 + 16 * j];
#pragma unroll
        for (int i = 0; i < 3; ++i)
#pragma unroll
            for (int j = 0; j < 12; ++j) {
                float e = __expf(AE[i][j] - u[i] - Mj[j]);
                AE[i][j] = (pv[i] && qv[j]) ? e : 0.f;
            }
        __syncthreads();

        // iters 2..20: multiplicative (sums + reciprocals only)
        float invS[3];
        for (int it = 0; it < ITERS - 1; ++it) {
#pragma unroll
            for (int i = 0; i < 3; ++i) {
                float s01 = AE[i][0] + AE[i][1], s23 = AE[i][2] + AE[i][3];
                float s45 = AE[i][4] + AE[i][5], s67 = AE[i][6] + AE[i][7];
                float s89 = AE[i][8] + AE[i][9], sab = AE[i][10] + AE[i][11];
                float S = ((s01 + s23) + (s45 + s67)) + (s89 + sab);
                S = rowsum16(S);
                invS[i] = nrcp(fmaxf(S, 1e-30f));
            }
#pragma unroll
            for (int j = 0; j < 12; ++j) {
                float pc = AE[0][j] * invS[0];
                pc = fmaf(AE[1][j], invS[1], pc);
                pc = fmaf(AE[2][j], invS[2], pc);
                region[rslot * 200 + l16 + 16 * j] = pc;
            }
            __syncthreads();
            if (t < 192) {
                float a0 = 0.f, a1 = 0.f, a2 = 0.f, a3 = 0.f;
#pragma unroll
                for (int s = 0; s < 16; ++s) {
                    a0 += region[(4 * s + 0) * 200 + t];
                    a1 += region[(4 * s + 1) * 200 + t];
                    a2 += region[(4 * s + 2) * 200 + t];
                    a3 += region[(4 * s + 3) * 200 + t];
                }
                float c = (a0 + a1) + (a2 + a3);
                sVbuf[t] = nrcp(fmaxf(c, 1e-30f));
            }
            __syncthreads();
            float ic[12];
#pragma unroll
            for (int j = 0; j < 12; ++j) ic[j] = sVbuf[l16 + 16 * j];
#pragma unroll
            for (int i = 0; i < 3; ++i)
#pragma unroll
                for (int j = 0; j < 12; ++j) {
                    float tmp = AE[i][j] * invS[i];
                    AE[i][j] = tmp * ic[j];
                }
        }

        float* ep = eplan + (size_t)b * NC2 * NC2;
#pragma unroll
        for (int i = 0; i < 3; ++i) {
            if (pv[i]) {
                int p = rslot + 64 * i;
                float* row = ep + (size_t)p * NC2;
#pragma unroll
                for (int j = 0; j < 12; ++j)
                    if (qv[j]) row[l16 + 16 * j] = AE[i][j];
            }
        }
    } else {
        // ======================= edge MLP role =======================
        int eb = blockIdx.x - 32, b = eb >> 2, qt = eb & 3;
        float b1 = bl1[l];
        float w128 = Wl1[128 * 64 + l];
        float b2 = 2.f * bl2[l];

        int base = qt * 96 + w * 6;
        float sv[6], dv[6], av[6]; bool val[6]; int gg[6], pp[6];
#pragma unroll
        for (int s = 0; s < 6; ++s) {
            int pl = base + s;
            val[s] = (pl < 380);
            int plc = val[s] ? pl : 0;
            gg[s] = (plc >= 190) ? 1 : 0;
            pp[s] = plc - gg[s] * 190;
            int sp = sQs[pp[s]], dp = sQd[pp[s]];
            sv[s] = h[(b * 40 + gg[s] * 20 + sp) * 64 + l];
            dv[s] = h[(b * 40 + gg[s] * 20 + dp) * 64 + l];
            const float* adj = gg[s] ? cadj : qadj;
            av[s] = adj[b * 400 + sp * 20 + dp];
        }
        float aF[6], aB[6];
#pragma unroll
        for (int s = 0; s < 6; ++s) { float t0 = b1 + av[s] * w128; aF[s] = t0; aB[s] = t0; }
#pragma unroll 2
        for (int k = 0; k < 64; ++k) {
            float w0 = Wl1[k * 64 + l];
            float w1 = Wl1[(64 + k) * 64 + l];
#pragma unroll
            for (int s = 0; s < 6; ++s) {
                float a = rlane(sv[s], k), c = rlane(dv[s], k);
                aF[s] += a * w0 + c * w1;
                aB[s] += c * w0 + a * w1;
            }
        }
        float hs[6], out[6];
#pragma unroll
        for (int s = 0; s < 6; ++s) { hs[s] = fmaxf(aF[s], 0.f) + fmaxf(aB[s], 0.f); out[s] = b2; }
#pragma unroll 4
        for (int k = 0; k < 64; ++k) {
            float ww = Wl2[k * 64 + l];
#pragma unroll
            for (int s = 0; s < 6; ++s) out[s] += rlane(hs[s], k) * ww;
        }
#pragma unroll
        for (int s = 0; s < 6; ++s)
            if (val[s]) emb[((size_t)(2 * b + gg[s]) * NC2 + pp[s]) * 64 + l] = out[s];
    }
}

// ================= final weighted L1 contraction =================
__global__ __launch_bounds__(256) void k_dist(
    const float* __restrict__ emb, const float* __restrict__ eplan, float* __restrict__ dout)
{
    int b = blockIdx.x, c = blockIdx.y;
    int w = threadIdx.x >> 6, l = threadIdx.x & 63;
    const float* qe = emb + (size_t)(2 * b) * NC2 * D_;
    const float* ce = emb + (size_t)(2 * b + 1) * NC2 * D_;
    const float* W = eplan + (size_t)b * NC2 * NC2;
    float acc = 0.f;
    int pbase = c * 16 + w * 4;
    for (int i = 0; i < 4; ++i) {
        int p = pbase + i;
        if (p >= NC2) break;
        float qv = qe[(size_t)p * D_ + l];
        const float* wrow = W + (size_t)p * NC2;
        for (int q = 0; q < NC2; ++q)
            acc += wrow[q] * fabsf(qv - ce[(size_t)q * D_ + l]);
    }
#pragma unroll
    for (int off = 32; off; off >>= 1) acc += __shfl_xor(acc, off);
    if (l == 0) atomicAdd(&dout[b], acc);
}

// ================= launch =================
extern "C" void kernel_launch(void* const* d_in, const int* in_sizes, int n_in,
                              void* d_out, int out_size, void* d_ws, size_t ws_size,
                              hipStream_t stream)
{
    const float* nf   = (const float*)d_in[0];
    const float* ef   = (const float*)d_in[1];
    const float* qadj = (const float*)d_in[2];
    const float* cadj = (const float*)d_in[3];
    const int*   fidx = (const int*)d_in[4];
    const int*   tidx = (const int*)d_in[5];
    const float* Wn  = (const float*)d_in[6];  const float* bn  = (const float*)d_in[7];
    const float* We  = (const float*)d_in[8];  const float* be  = (const float*)d_in[9];
    const float* Wm1 = (const float*)d_in[10]; const float* bm1 = (const float*)d_in[11];
    const float* Wm2 = (const float*)d_in[12]; const float* bm2 = (const float*)d_in[13];
    const float* Wu1 = (const float*)d_in[14]; const float* bu1 = (const float*)d_in[15];
    const float* Wu2 = (const float*)d_in[16]; const float* bu2 = (const float*)d_in[17];
    const float* Ws1 = (const float*)d_in[18]; const float* bs1 = (const float*)d_in[19];
    const float* Ws2 = (const float*)d_in[20]; const float* bs2 = (const float*)d_in[21];
    const float* Wl1 = (const float*)d_in[22]; const float* bl1 = (const float*)d_in[23];
    const float* Wl2 = (const float*)d_in[24]; const float* bl2 = (const float*)d_in[25];

    float* ws    = (float*)d_ws;
    float* h     = ws;                               // TN*64
    float* emb   = h + (size_t)TN * 64;              // NG*NC2*64
    float* eplan = emb + (size_t)NG * NC2 * 64;      // B*NC2*NC2
    float* dout  = (float*)d_out;

    k_prop<<<NG, 640, 0, stream>>>(nf, ef, fidx, tidx, Wn, bn, We, be,
                                   Wm1, bm1, Wm2, bm2, Wu1, bu1, Wu2, bu2, h);
    k_fuse<<<160, 1024, 0, stream>>>(h, qadj, cadj, Ws1, bs1, Ws2, bs2,
                                     Wl1, bl1, Wl2, bl2, emb, eplan, dout);
    k_dist<<<dim3(B_, 12), 256, 0, stream>>>(emb, eplan, dout);
}

// Round 8
// 350.929 us; speedup vs baseline: 1.6614x; 1.0702x over previous
//
#include <hip/hip_runtime.h>
#include <math.h>

#define B_     32
#define N_     20
#define D_     64
#define NODE_F 16
#define EDGE_F 8
#define E_PER  40
#define PROP   5
#define NC2    190
#define ITERS  20
#define INV_TEMP 10.0f
#define TN (2*B_*N_)
#define NG (2*B_)

struct PairTab { int s[NC2]; int d[NC2]; };
constexpr PairTab make_pairs() {
    PairTab t{};
    int idx = 0;
    for (int i = 0; i < N_; ++i)
        for (int j = i + 1; j < N_; ++j) { t.s[idx] = i; t.d[idx] = j; ++idx; }
    return t;
}
__device__ constexpr PairTab PAIRS = make_pairs();

__device__ __forceinline__ float rlane(float x, int k) {
    return __int_as_float(__builtin_amdgcn_readlane(__float_as_int(x), k));
}
template<int CTRL>
__device__ __forceinline__ float dppmov(float x) {
    return __int_as_float(__builtin_amdgcn_update_dpp(
        0, __float_as_int(x), CTRL, 0xf, 0xf, false));
}
__device__ __forceinline__ float rowsum16(float x) {
    x += dppmov<0x121>(x); x += dppmov<0x122>(x);
    x += dppmov<0x124>(x); x += dppmov<0x128>(x);
    return x;
}
__device__ __forceinline__ float rowmax16(float x) {
    x = fmaxf(x, dppmov<0x121>(x)); x = fmaxf(x, dppmov<0x122>(x));
    x = fmaxf(x, dppmov<0x124>(x)); x = fmaxf(x, dppmov<0x128>(x));
    return x;
}
__device__ __forceinline__ float nrcp(float x) {
    float r = __builtin_amdgcn_rcpf(x);
    r = r * fmaf(-x, r, 2.0f);
    return r;
}

// ================= per-graph: encode + 5x(msg,update); weights LDS-staged per phase =================
// layer1 of msg MLP decomposed: pre = F1[from] + T1[to] + E1[edge], E1 constant across steps.
__global__ __launch_bounds__(1024, 4) void k_prop(
    const float* __restrict__ nf, const float* __restrict__ ef,
    const int* __restrict__ fidx, const int* __restrict__ tidx,
    const float* __restrict__ Wn, const float* __restrict__ bn,
    const float* __restrict__ We, const float* __restrict__ be,
    const float* __restrict__ Wm1, const float* __restrict__ bm1,
    const float* __restrict__ Wm2, const float* __restrict__ bm2,
    const float* __restrict__ Wu1, const float* __restrict__ bu1,
    const float* __restrict__ Wu2, const float* __restrict__ bu2,
    float* __restrict__ hout)
{
    __shared__ __align__(16) float wbuf[8192];     // 32 KB staged weights
    __shared__ float sh[20][64];                   // node states
    __shared__ float sE1[40][64];                  // constant edge layer-1 part (incl bm1)
    __shared__ float sFT[40][64];                  // [0..19]=F1, [20..39]=T1
    __shared__ float sa[20][64];                   // aggregation
    __shared__ short sF[40], sD[40];
    int g = blockIdx.x, t = threadIdx.x, w = t >> 6, l = t & 63;

    if (t < 40) {
        sF[t] = (short)(fidx[g * 40 + t] - g * 20);
        sD[t] = (short)(tidx[g * 40 + t] - g * 20);
    }
    // ---- encode nodes (Wn 4KB from L1)
    for (int n = w; n < 20; n += 16) {
        float a = bn[l];
#pragma unroll
        for (int k = 0; k < NODE_F; ++k) a += nf[(g * 20 + n) * NODE_F + k] * Wn[k * 64 + l];
        sh[n][l] = a; sa[n][l] = 0.f;
    }
    // ---- stage Wm1[128:192], compute E1 (edge part of msg layer1, constant over steps)
    {
        const float4* s4 = (const float4*)(Wm1 + 128 * 64);
        float4* d4 = (float4*)wbuf;
        for (int i = t; i < 1024; i += 1024) d4[i] = s4[i];
    }
    __syncthreads();
    for (int e = w; e < 40; e += 16) {
        float em = be[l];
#pragma unroll
        for (int k = 0; k < EDGE_F; ++k) em += ef[(g * 40 + e) * EDGE_F + k] * We[k * 64 + l];
        float a = bm1[l];
#pragma unroll 4
        for (int k = 0; k < 64; ++k) a += rlane(em, k) * wbuf[k * 64 + l];
        sE1[e][l] = a;
    }

    for (int step = 0; step < PROP; ++step) {
        // ======== phase A: F1/T1 node partials (Wm1 rows 0..127, 32KB) ========
        __syncthreads();
        {
            const float4* s4 = (const float4*)Wm1;
            float4* d4 = (float4*)wbuf;
            for (int i = t; i < 2048; i += 1024) d4[i] = s4[i];
        }
        __syncthreads();
        {
            int part = w >> 3;          // 0 = F (rows 0..63), 1 = T (rows 64..127)
            int wl = w & 7;
            for (int n = wl; n < 20; n += 8) {
                float xh = sh[n][l];
                float a = 0.f;
#pragma unroll 4
                for (int k = 0; k < 64; ++k)
                    a += rlane(xh, k) * wbuf[(part * 64 + k) * 64 + l];
                sFT[part * 20 + n][l] = a;
            }
        }
        // ======== phase B: msg layer2 + aggregate (Wm2 16KB) ========
        __syncthreads();
        {
            const float4* s4 = (const float4*)Wm2;
            float4* d4 = (float4*)wbuf;
            for (int i = t; i < 1024; i += 1024) d4[i] = s4[i];
        }
        __syncthreads();
        for (int e = w; e < 40; e += 16) {
            int fr = sF[e], to = sD[e];
            float a1 = fmaxf(sFT[fr][l] + sFT[20 + to][l] + sE1[e][l], 0.f);
            float o = bm2[l];
#pragma unroll 4
            for (int k = 0; k < 64; ++k) o += rlane(a1, k) * wbuf[k * 64 + l];
            atomicAdd(&sa[to][l], o);
        }
        // ======== phase C: update layer1 (Wu1 32KB) ========
        __syncthreads();
        {
            const float4* s4 = (const float4*)Wu1;
            float4* d4 = (float4*)wbuf;
            for (int i = t; i < 2048; i += 1024) d4[i] = s4[i];
        }
        __syncthreads();
        float a2[2];
#pragma unroll
        for (int ii = 0; ii < 2; ++ii) {
            int n = w + 16 * ii;
            if (n < 20) {
                float xh = sh[n][l], xa = sa[n][l];
                float a = bu1[l];
#pragma unroll 4
                for (int k = 0; k < 64; ++k) {
                    a += rlane(xh, k) * wbuf[k * 64 + l];
                    a += rlane(xa, k) * wbuf[(64 + k) * 64 + l];
                }
                a2[ii] = fmaxf(a, 0.f);
            } else a2[ii] = 0.f;
        }
        // ======== phase D: update layer2 (Wu2 16KB) ========
        __syncthreads();
        {
            const float4* s4 = (const float4*)Wu2;
            float4* d4 = (float4*)wbuf;
            for (int i = t; i < 1024; i += 1024) d4[i] = s4[i];
        }
        __syncthreads();
#pragma unroll
        for (int ii = 0; ii < 2; ++ii) {
            int n = w + 16 * ii;
            if (n < 20) {
                float o = bu2[l];
#pragma unroll 4
                for (int k = 0; k < 64; ++k) o += rlane(a2[ii], k) * wbuf[k * 64 + l];
                sh[n][l] = o; sa[n][l] = 0.f;
            }
        }
    }
    __syncthreads();
    for (int n = w; n < 20; n += 16) hout[(g * 20 + n) * 64 + l] = sh[n][l];
}

// ================= heterogeneous: blocks 0..31 sim+sink190, blocks 32..159 edge MLP =================
__global__ __launch_bounds__(1024, 4) void k_fuse(
    const float* __restrict__ h,
    const float* __restrict__ qadj, const float* __restrict__ cadj,
    const float* __restrict__ Ws1, const float* __restrict__ bs1,
    const float* __restrict__ Ws2, const float* __restrict__ bs2,
    const float* __restrict__ Wl1, const float* __restrict__ bl1,
    const float* __restrict__ Wl2, const float* __restrict__ bl2,
    float* __restrict__ emb, float* __restrict__ eplan, float* __restrict__ dout)
{
    __shared__ short sQs[192], sQd[192];
    __shared__ float sP[N_][N_];
    __shared__ float sVbuf[192];
    __shared__ __align__(16) float region[12800];  // sim: sT+sLa | sink: colbuf[16][200] | edge: staged Wl1/Wl2
    int t = threadIdx.x, w = t >> 6, l = t & 63;

    if (t < 192) {
        int tt = t < NC2 ? t : NC2 - 1;
        sQs[t] = (short)PAIRS.s[tt]; sQd[t] = (short)PAIRS.d[tt];
    }
    __syncthreads();

    if (blockIdx.x < 32) {
        // ======================= sim + sink190 role =======================
        int b = blockIdx.x;
        if (t == 0) dout[b] = 0.f;
        float* sT = region;
        float* sLa = region + 800;

        // T MLPs (h from global, L1-hot; Ws small)
        {
            int lk = (l < 20) ? l : 0;
#pragma unroll
            for (int s = 0; s < 3; ++s) {
                int r = w + 16 * s;
                if (r < 40) {
                    float hv = h[(b * 40 + r) * 64 + l];
                    float a = bs1[lk];
#pragma unroll 4
                    for (int ff = 0; ff < 64; ++ff) a += rlane(hv, ff) * Ws1[ff * 20 + lk];
                    a = fmaxf(a, 0.f);
                    float t2 = bs2[lk];
#pragma unroll
                    for (int j = 0; j < 20; ++j) t2 += rlane(a, j) * Ws2[j * 20 + lk];
                    if (l < 20) sT[(r >= 20) * 400 + (r % 20) * 20 + l] = t2;
                }
            }
        }
        __syncthreads();
        if (t < 400) {
            int i = t / 20, j = t % 20;
            float c = 0.f;
#pragma unroll
            for (int k = 0; k < 20; ++k) c += fabsf(sT[i * 20 + k] - sT[400 + j * 20 + k]);
            sLa[i * 20 + j] = -c * INV_TEMP;
        }
        __syncthreads();

        // single-wave register 20x20 log sinkhorn
        if (w == 0) {
            int q = l & 31, r2 = l >> 5;
            bool qok = (q < 20);
            float A20[10], u10[10];
#pragma unroll
            for (int i = 0; i < 10; ++i) {
                int r = 2 * i + r2;
                A20[i] = qok ? sLa[r * 20 + q] : -1e30f;
            }
            float vq = 0.f;
            for (int it = 0; it < ITERS; ++it) {
#pragma unroll
                for (int i = 0; i < 10; ++i) {
                    float x = A20[i] - vq;
                    float m = x;
#pragma unroll
                    for (int off = 16; off; off >>= 1) m = fmaxf(m, __shfl_xor(m, off));
                    float s = __expf(x - m);
#pragma unroll
                    for (int off = 16; off; off >>= 1) s += __shfl_xor(s, off);
                    u10[i] = m + __logf(s);
                }
                float pm = -1e30f;
#pragma unroll
                for (int i = 0; i < 10; ++i) pm = fmaxf(pm, A20[i] - u10[i]);
                float ps = 0.f;
#pragma unroll
                for (int i = 0; i < 10; ++i) ps += __expf(A20[i] - u10[i] - pm);
                float om = __shfl_xor(pm, 32), os = __shfl_xor(ps, 32);
                float M = fmaxf(pm, om);
                float S = ps * __expf(pm - M) + os * __expf(om - M);
                vq = M + __logf(S);
                if (!qok) vq = 0.f;
            }
#pragma unroll
            for (int i = 0; i < 10; ++i) {
                int r = 2 * i + r2;
                if (qok) sP[r][q] = __expf(A20[i] - u10[i] - vq);
            }
        }
        __syncthreads();

        // ---- sink190 (register state; wave shfl pre-reduce for columns) ----
        int g4 = l >> 4, l16 = l & 15, rslot = w * 4 + g4;
        int sp[3], dp[3]; bool pv[3];
#pragma unroll
        for (int i = 0; i < 3; ++i) {
            int p = rslot + 64 * i;
            pv[i] = (p < NC2);
            int pc = pv[i] ? p : 0;
            sp[i] = sQs[pc]; dp[i] = sQd[pc];
        }
        int sq[12], dq[12]; bool qv[12];
#pragma unroll
        for (int j = 0; j < 12; ++j) {
            int q = l16 + 16 * j;
            qv[j] = (q < NC2);
            int qc = qv[j] ? q : 0;
            sq[j] = sQs[qc]; dq[j] = sQd[qc];
        }

        float AE[3][12];
#pragma unroll
        for (int i = 0; i < 3; ++i)
#pragma unroll
            for (int j = 0; j < 12; ++j) {
                if (pv[i] && qv[j]) {
                    float st = sP[sp[i]][sq[j]] * sP[dp[i]][dq[j]];
                    float cr = sP[sp[i]][dq[j]] * sP[dp[i]][sq[j]];
                    AE[i][j] = __logf(fmaxf(st, cr) + 1e-6f) * INV_TEMP;
                } else AE[i][j] = -1e30f;
            }

        // iter 1 in log domain
        float u[3];
#pragma unroll
        for (int i = 0; i < 3; ++i) {
            float m = -1e30f;
#pragma unroll
            for (int j = 0; j < 12; ++j) m = fmaxf(m, AE[i][j]);
            m = rowmax16(m);
            float s = 0.f;
#pragma unroll
            for (int j = 0; j < 12; ++j) s += __expf(AE[i][j] - m);
            s = rowsum16(s);
            u[i] = m + __logf(s);
            if (!pv[i]) u[i] = 0.f;
        }
#pragma unroll
        for (int j = 0; j < 12; ++j) {
            float pm = -1e30f;
#pragma unroll
            for (int i = 0; i < 3; ++i) if (pv[i]) pm = fmaxf(pm, AE[i][j] - u[i]);
            pm = fmaxf(pm, __shfl_xor(pm, 16));
            pm = fmaxf(pm, __shfl_xor(pm, 32));
            if (g4 == 0) region[w * 200 + l16 + 16 * j] = pm;
        }
        __syncthreads();
        if (t < 192) {
            float M = -1e30f;
#pragma unroll
            for (int s = 0; s < 16; ++s) M = fmaxf(M, region[s * 200 + t]);
            sVbuf[t] = M;
        }
        __syncthreads();
        float Mj[12];
#pragma unroll
        for (int j = 0; j < 12; ++j) Mj[j] = sVbuf[l16 + 16 * j];
#pragma unroll
        for (int j = 0; j < 12; ++j) {
            float ps = 0.f;
#pragma unroll
            for (int i = 0; i < 3; ++i) if (pv[i]) ps += __expf(AE[i][j] - u[i] - Mj[j]);
            ps += __shfl_xor(ps, 16);
            ps += __shfl_xor(ps, 32);
            if (g4 == 0) region[w * 200 + l16 + 16 * j] = ps;
        }
        __syncthreads();
        if (t < 192) {
            float S = 0.f;
#pragma unroll
            for (int s = 0; s < 16; ++s) S += region[s * 200 + t];
            sVbuf[t] = sVbuf[t] + __logf(fmaxf(S, 1e-37f));
        }
        __syncthreads();
#pragma unroll
        for (int j = 0; j < 12; ++j) Mj[j] = sVbuf[l16 + 16 * j];
#pragma unroll
        for (int i = 0; i < 3; ++i)
#pragma unroll
            for (int j = 0; j < 12; ++j) {
                float e = __expf(AE[i][j] - u[i] - Mj[j]);
                AE[i][j] = (pv[i] && qv[j]) ? e : 0.f;
            }
        __syncthreads();

        // iters 2..20 multiplicative
        float invS[3];
        for (int it = 0; it < ITERS - 1; ++it) {
#pragma unroll
            for (int i = 0; i < 3; ++i) {
                float s01 = AE[i][0] + AE[i][1], s23 = AE[i][2] + AE[i][3];
                float s45 = AE[i][4] + AE[i][5], s67 = AE[i][6] + AE[i][7];
                float s89 = AE[i][8] + AE[i][9], sab = AE[i][10] + AE[i][11];
                float S = ((s01 + s23) + (s45 + s67)) + (s89 + sab);
                S = rowsum16(S);
                invS[i] = nrcp(fmaxf(S, 1e-30f));
            }
#pragma unroll
            for (int j = 0; j < 12; ++j) {
                float pc = AE[0][j] * invS[0];
                pc = fmaf(AE[1][j], invS[1], pc);
                pc = fmaf(AE[2][j], invS[2], pc);
                pc += __shfl_xor(pc, 16);
                pc += __shfl_xor(pc, 32);
                if (g4 == 0) region[w * 200 + l16 + 16 * j] = pc;
            }
            __syncthreads();
            if (t < 192) {
                float c = 0.f;
#pragma unroll
                for (int s = 0; s < 16; ++s) c += region[s * 200 + t];
                sVbuf[t] = nrcp(fmaxf(c, 1e-30f));
            }
            __syncthreads();
            float ic[12];
#pragma unroll
            for (int j = 0; j < 12; ++j) ic[j] = sVbuf[l16 + 16 * j];
#pragma unroll
            for (int i = 0; i < 3; ++i)
#pragma unroll
                for (int j = 0; j < 12; ++j) {
                    float tmp = AE[i][j] * invS[i];
                    AE[i][j] = tmp * ic[j];
                }
        }

        float* ep = eplan + (size_t)b * NC2 * NC2;
#pragma unroll
        for (int i = 0; i < 3; ++i) {
            if (pv[i]) {
                int p = rslot + 64 * i;
                float* row = ep + (size_t)p * NC2;
#pragma unroll
                for (int j = 0; j < 12; ++j)
                    if (qv[j]) row[l16 + 16 * j] = AE[i][j];
            }
        }
    } else {
        // ======================= edge MLP role (weights LDS-staged) =======================
        int eb = blockIdx.x - 32, b = eb >> 2, qt = eb & 3;
        float* wb1 = region;            // Wl1 rows 0..127 (8192 floats)
        float* wb2 = region + 8192;     // Wl2 (4096 floats)
        {
            const float4* s1 = (const float4*)Wl1;
            float4* d1 = (float4*)wb1;
            for (int i = t; i < 2048; i += 1024) d1[i] = s1[i];
            const float4* s2 = (const float4*)Wl2;
            float4* d2 = (float4*)wb2;
            if (t < 1024) d2[t] = s2[t];
        }
        float b1 = bl1[l];
        float w128 = Wl1[128 * 64 + l];
        float b2 = 2.f * bl2[l];
        __syncthreads();

        int base = qt * 96 + w * 6;
        float sv[6], dv[6], av[6]; bool val[6]; int gg[6], pp[6];
#pragma unroll
        for (int s = 0; s < 6; ++s) {
            int pl = base + s;
            val[s] = (pl < 380);
            int plc = val[s] ? pl : 0;
            gg[s] = (plc >= 190) ? 1 : 0;
            pp[s] = plc - gg[s] * 190;
            int sp = sQs[pp[s]], dp = sQd[pp[s]];
            sv[s] = h[(b * 40 + gg[s] * 20 + sp) * 64 + l];
            dv[s] = h[(b * 40 + gg[s] * 20 + dp) * 64 + l];
            const float* adj = gg[s] ? cadj : qadj;
            av[s] = adj[b * 400 + sp * 20 + dp];
        }
        float aF[6], aB[6];
#pragma unroll
        for (int s = 0; s < 6; ++s) { float t0 = b1 + av[s] * w128; aF[s] = t0; aB[s] = t0; }
#pragma unroll 2
        for (int k = 0; k < 64; ++k) {
            float w0 = wb1[k * 64 + l];
            float w1 = wb1[(64 + k) * 64 + l];
#pragma unroll
            for (int s = 0; s < 6; ++s) {
                float a = rlane(sv[s], k), c = rlane(dv[s], k);
                aF[s] += a * w0 + c * w1;
                aB[s] += c * w0 + a * w1;
            }
        }
        float hs[6], out[6];
#pragma unroll
        for (int s = 0; s < 6; ++s) { hs[s] = fmaxf(aF[s], 0.f) + fmaxf(aB[s], 0.f); out[s] = b2; }
#pragma unroll 4
        for (int k = 0; k < 64; ++k) {
            float ww = wb2[k * 64 + l];
#pragma unroll
            for (int s = 0; s < 6; ++s) out[s] += rlane(hs[s], k) * ww;
        }
#pragma unroll
        for (int s = 0; s < 6; ++s)
            if (val[s]) emb[((size_t)(2 * b + gg[s]) * NC2 + pp[s]) * 64 + l] = out[s];
    }
}

// ================= final weighted L1 contraction =================
__global__ __launch_bounds__(256) void k_dist(
    const float* __restrict__ emb, const float* __restrict__ eplan, float* __restrict__ dout)
{
    int b = blockIdx.x, c = blockIdx.y;
    int w = threadIdx.x >> 6, l = threadIdx.x & 63;
    const float* qe = emb + (size_t)(2 * b) * NC2 * D_;
    const float* ce = emb + (size_t)(2 * b + 1) * NC2 * D_;
    const float* W = eplan + (size_t)b * NC2 * NC2;
    float acc = 0.f;
    int pbase = c * 16 + w * 4;
    for (int i = 0; i < 4; ++i) {
        int p = pbase + i;
        if (p >= NC2) break;
        float qv = qe[(size_t)p * D_ + l];
        const float* wrow = W + (size_t)p * NC2;
        for (int q = 0; q < NC2; ++q)
            acc += wrow[q] * fabsf(qv - ce[(size_t)q * D_ + l]);
    }
#pragma unroll
    for (int off = 32; off; off >>= 1) acc += __shfl_xor(acc, off);
    if (l == 0) atomicAdd(&dout[b], acc);
}

// ================= launch =================
extern "C" void kernel_launch(void* const* d_in, const int* in_sizes, int n_in,
                              void* d_out, int out_size, void* d_ws, size_t ws_size,
                              hipStream_t stream)
{
    const float* nf   = (const float*)d_in[0];
    const float* ef   = (const float*)d_in[1];
    const float* qadj = (const float*)d_in[2];
    const float* cadj = (const float*)d_in[3];
    const int*   fidx = (const int*)d_in[4];
    const int*   tidx = (const int*)d_in[5];
    const float* Wn  = (const float*)d_in[6];  const float* bn  = (const float*)d_in[7];
    const float* We  = (const float*)d_in[8];  const float* be  = (const float*)d_in[9];
    const float* Wm1 = (const float*)d_in[10]; const float* bm1 = (const float*)d_in[11];
    const float* Wm2 = (const float*)d_in[12]; const float* bm2 = (const float*)d_in[13];
    const float* Wu1 = (const float*)d_in[14]; const float* bu1 = (const float*)d_in[15];
    const float* Wu2 = (const float*)d_in[16]; const float* bu2 = (const float*)d_in[17];
    const float* Ws1 = (const float*)d_in[18]; const float* bs1 = (const float*)d_in[19];
    const float* Ws2 = (const float*)d_in[20]; const float* bs2 = (const float*)d_in[21];
    const float* Wl1 = (const float*)d_in[22]; const float* bl1 = (const float*)d_in[23];
    const float* Wl2 = (const float*)d_in[24]; const float* bl2 = (const float*)d_in[25];

    float* ws    = (float*)d_ws;
    float* h     = ws;                               // TN*64
    float* emb   = h + (size_t)TN * 64;              // NG*NC2*64
    float* eplan = emb + (size_t)NG * NC2 * 64;      // B*NC2*NC2
    float* dout  = (float*)d_out;

    k_prop<<<NG, 1024, 0, stream>>>(nf, ef, fidx, tidx, Wn, bn, We, be,
                                    Wm1, bm1, Wm2, bm2, Wu1, bu1, Wu2, bu2, h);
    k_fuse<<<160, 1024, 0, stream>>>(h, qadj, cadj, Ws1, bs1, Ws2, bs2,
                                     Wl1, bl1, Wl2, bl2, emb, eplan, dout);
    k_dist<<<dim3(B_, 12), 256, 0, stream>>>(emb, eplan, dout);
}